// Round 3
// baseline (3628.143 us; speedup 1.0000x reference)
//
#include <hip/hip_runtime.h>
#include <stdint.h>

#define N_NODES 50000
#define N_EDGES 200000
#define H 32
#define T_STEPS 8
#define NGROUPS (N_EDGES / 64)   // 3125, exact: no tail handling anywhere

typedef __attribute__((ext_vector_type(4))) float v4f;
typedef __attribute__((ext_vector_type(8))) _Float16 h8;

#define LO_SCALE 4096.0f
#define LO_DESCALE 2.44140625e-4f  // 1/4096

__device__ __forceinline__ uint32_t packh2(_Float16 a, _Float16 b) {
  return (uint32_t)__builtin_bit_cast(unsigned short, a) |
         ((uint32_t)__builtin_bit_cast(unsigned short, b) << 16);
}

// hid[e][d] = relu(edge_data[e].W1[d] + b1[d]), fp16 hi + scaled-lo. (proven)
__global__ void hidb_kernel(const float* __restrict__ ed, const float* __restrict__ W1,
                            const float* __restrict__ b1,
                            uint32_t* __restrict__ hidh, uint32_t* __restrict__ hidl) {
  int idx = blockIdx.x * blockDim.x + threadIdx.x;   // E*32 threads
  int e = idx >> 5, d2 = idx & 31;
  int d0 = d2 * 2;
  const float4* er = (const float4*)(ed + (size_t)e * 16);
  const float4* w0 = (const float4*)(W1 + (size_t)d0 * 16);
  const float4* w1 = (const float4*)(W1 + (size_t)(d0 + 1) * 16);
  float a0 = b1[d0], a1 = b1[d0 + 1];
#pragma unroll
  for (int k = 0; k < 4; k++) {
    float4 h = er[k], u = w0[k], v = w1[k];
    a0 += h.x * u.x + h.y * u.y + h.z * u.z + h.w * u.w;
    a1 += h.x * v.x + h.y * v.y + h.z * v.z + h.w * v.w;
  }
  a0 = fmaxf(a0, 0.f);
  a1 = fmaxf(a1, 0.f);
  _Float16 h0 = (_Float16)a0, h1 = (_Float16)a1;
  _Float16 l0 = (_Float16)((a0 - (float)h0) * LO_SCALE);
  _Float16 l1 = (_Float16)((a1 - (float)h1) * LO_SCALE);
  hidh[idx] = packh2(h0, h1);
  hidl[idx] = packh2(l0, l1);
}

// Pack W2 into MFMA A-fragment-linear fp16 hi / scaled-lo. (proven)
__global__ void w2pack_kernel(const float* __restrict__ W2,
                              uint32_t* __restrict__ W2Fh, uint32_t* __restrict__ W2Fl) {
  int o = blockIdx.x * blockDim.x + threadIdx.x;   // 32768 threads
  int c = o >> 8, u = o & 255;
  int lane = u >> 2, pr = u & 3;
  int mtg = c >> 1, kh = c & 1;
  int row = mtg * 16 + (lane & 15);
  int k = kh * 32 + (lane >> 4) * 8 + pr * 2;
  float v0 = W2[(size_t)row * 64 + k];
  float v1 = W2[(size_t)row * 64 + k + 1];
  _Float16 h0 = (_Float16)v0, h1 = (_Float16)v1;
  _Float16 l0 = (_Float16)((v0 - (float)h0) * LO_SCALE);
  _Float16 l1 = (_Float16)((v1 - (float)h1) * LO_SCALE);
  W2Fh[o] = packh2(h0, h1);
  W2Fl[o] = packh2(l0, l1);
}

// ---------- CSR incidence build (proven R11) ----------
__global__ void zero_cur_kernel(int* __restrict__ cur) {
  int i = blockIdx.x * blockDim.x + threadIdx.x;
  if (i < N_NODES) cur[i] = 0;
}
__global__ void count_kernel(const int* __restrict__ edges, int* __restrict__ cur) {
  int e = blockIdx.x * blockDim.x + threadIdx.x;
  if (e < N_EDGES) {
    int s = edges[2 * e], d = edges[2 * e + 1];
    atomicAdd(&cur[s], 1);
    if (d != s) atomicAdd(&cur[d], 1);
  }
}
__global__ __launch_bounds__(1024) void scan_kernel(int* __restrict__ cur,
                                                    int* __restrict__ off) {
  __shared__ int lds[1024];
  int t = threadIdx.x;
  int base = t * 49;
  int cnt = 0;
  for (int j = 0; j < 49; j++) {
    int idx = base + j;
    if (idx < N_NODES) cnt += cur[idx];
  }
  lds[t] = cnt;
  __syncthreads();
  for (int d = 1; d < 1024; d <<= 1) {
    int v = (t >= d) ? lds[t - d] : 0;
    __syncthreads();
    lds[t] += v;
    __syncthreads();
  }
  int run = lds[t] - cnt;   // exclusive prefix of this thread's chunk
  for (int j = 0; j < 49; j++) {
    int idx = base + j;
    if (idx < N_NODES) {
      int c = cur[idx];
      off[idx] = run;
      cur[idx] = run;
      run += c;
    }
  }
  if (t == 1023) off[N_NODES] = lds[1023];
}
__global__ void scatter_kernel(const int* __restrict__ edges, int* __restrict__ cur,
                               int* __restrict__ inc) {
  int e = blockIdx.x * blockDim.x + threadIdx.x;
  if (e < N_EDGES) {
    int s = edges[2 * e], d = edges[2 * e + 1];
    int p = atomicAdd(&cur[s], 1);
    inc[p] = e;
    if (d != s) {
      p = atomicAdd(&cur[d], 1);
      inc[p] = e;
    }
  }
}

// ---------- message build: EXACT proven R0 structure (256 thr, grid 1024,
// NGROUPS loop, quarter-major msg) + in-wave software pipelining ----------
// R1/R2 lesson: the 8-wave/512-thread fusion fails with identical absmax
// under two different msg layouts -> restructure is quarantined, do not
// revisit without isolating the bug offline.
// This round's single change: rotate the ENTIRE next-iteration input set
// (src index, hid hi/lo fragments, x[src] vectors) into registers, issued
// BEFORE the current iteration's 96-MFMA loop. With only 2 waves/SIMD
// (LDS-capped), TLP cannot hide the ~2000-cycle serial load chain; this
// hides it under the MFMA work instead. Indexing is verbatim R0; only load
// scheduling changes. VGPR ~128->~160, free (occupancy is LDS-capped).
__global__ __launch_bounds__(256, 2) void msg_kernel(
    const uint32_t* __restrict__ W2Fh, const uint32_t* __restrict__ W2Fl,
    const uint32_t* __restrict__ hidh, const uint32_t* __restrict__ hidl,
    const float* __restrict__ b2, const float* __restrict__ x,
    const int* __restrict__ edges, float* __restrict__ msg) {
  __shared__ uint32_t w2h[8192];   // 32 KB: this block's M-quarter, hi
  __shared__ uint32_t w2l[8192];   // 32 KB: scaled lo
  __shared__ float b2s[256];
  int t = threadIdx.x;
  int bid = blockIdx.x;
  int xcd = bid & 7;
  int mq = (bid >> 3) & 3;
  int stream = bid >> 5;            // 0..31
  int gstart = xcd + (stream << 3); // 0..255, unique per (xcd,stream)
  for (int p = t; p < 8192; p += 256) {
    w2h[p] = W2Fh[mq * 8192 + p];
    w2l[p] = W2Fl[mq * 8192 + p];
  }
  b2s[t] = b2[mq * 256 + t];
  __syncthreads();

  int wv = t >> 6, lane = t & 63;
  int el = lane & 15, kg = lane >> 4;
  const h8* sh = (const h8*)w2h;
  const h8* sl = (const h8*)w2l;
  const h8* hbh = (const h8*)hidh;
  const h8* hbl = (const h8*)hidl;

  // prologue: load iteration gstart's inputs (latency exposed once per block)
  int e = gstart * 64 + wv * 16 + el;           // e < NGROUPS*64 always
  int src = edges[2 * e];
  h8 bh0 = hbh[(size_t)e * 8 + kg];
  h8 bh1 = hbh[(size_t)e * 8 + 4 + kg];
  h8 bl0 = hbl[(size_t)e * 8 + kg];
  h8 bl1 = hbl[(size_t)e * 8 + 4 + kg];
  v4f xr0 = *(const v4f*)(x + (size_t)src * 32 + kg * 4);
  v4f xr1 = *(const v4f*)(x + (size_t)src * 32 + 16 + kg * 4);

  for (int g = gstart; g < NGROUPS; g += 256) {
    // ---- issue next iteration's loads first (hide under MFMAs below) ----
    int gn = g + 256;
    bool more = gn < NGROUPS;
    int en = 0, srcn = 0;
    h8 nbh0, nbh1, nbl0, nbl1;
    v4f nxr0, nxr1;
    if (more) {
      en = gn * 64 + wv * 16 + el;
      srcn = edges[2 * en];
      nbh0 = hbh[(size_t)en * 8 + kg];
      nbh1 = hbh[(size_t)en * 8 + 4 + kg];
      nbl0 = hbl[(size_t)en * 8 + kg];
      nbl1 = hbl[(size_t)en * 8 + 4 + kg];
      nxr0 = *(const v4f*)(x + (size_t)srcn * 32 + kg * 4);
      nxr1 = *(const v4f*)(x + (size_t)srcn * 32 + 16 + kg * 4);
    }

    // ---- compute current iteration (math verbatim proven R0) ----
    float sacc[8];
#pragma unroll
    for (int mp = 0; mp < 8; mp++) {
      float tacc = 0.f;
#pragma unroll
      for (int tp = 0; tp < 2; tp++) {
        int mt = 2 * mp + tp;
        h8 ah0 = sh[(size_t)(mt * 2 + 0) * 64 + lane];
        h8 ah1 = sh[(size_t)(mt * 2 + 1) * 64 + lane];
        h8 al0 = sl[(size_t)(mt * 2 + 0) * 64 + lane];
        h8 al1 = sl[(size_t)(mt * 2 + 1) * 64 + lane];
        v4f chi = *(const v4f*)(b2s + mt * 16 + kg * 4);   // bias as C-init
        chi = __builtin_amdgcn_mfma_f32_16x16x32_f16(ah0, bh0, chi, 0, 0, 0);
        chi = __builtin_amdgcn_mfma_f32_16x16x32_f16(ah1, bh1, chi, 0, 0, 0);
        v4f clo = {0.f, 0.f, 0.f, 0.f};
        clo = __builtin_amdgcn_mfma_f32_16x16x32_f16(ah0, bl0, clo, 0, 0, 0);
        clo = __builtin_amdgcn_mfma_f32_16x16x32_f16(ah1, bl1, clo, 0, 0, 0);
        clo = __builtin_amdgcn_mfma_f32_16x16x32_f16(al0, bh0, clo, 0, 0, 0);
        clo = __builtin_amdgcn_mfma_f32_16x16x32_f16(al1, bh1, clo, 0, 0, 0);
        v4f xr = tp ? xr1 : xr0;
#pragma unroll
        for (int r = 0; r < 4; r++) {
          float av = fmaxf(fmaf(clo[r], LO_DESCALE, chi[r]), 0.f);
          tacc = fmaf(av, xr[r], tacc);
        }
      }
      float s = tacc;
      s += __shfl_xor(s, 16, 64);
      s += __shfl_xor(s, 32, 64);
      sacc[mp] = s;   // msg value for (e, i = mq*8+mp)
    }
    if (lane < 16) {
      // quarter-major: msg[mq][e][0..7]; wave's 16 edges -> 512 contiguous B
      float* mrow = msg + ((size_t)mq * N_EDGES + e) * 8;
      v4f s0 = {sacc[0], sacc[1], sacc[2], sacc[3]};
      v4f s1 = {sacc[4], sacc[5], sacc[6], sacc[7]};
      *(v4f*)(mrow + 0) = s0;
      *(v4f*)(mrow + 4) = s1;
    }

    // ---- rotate next -> current ----
    if (more) {
      e = en; src = srcn;
      bh0 = nbh0; bh1 = nbh1; bl0 = nbl0; bl1 = nbl1;
      xr0 = nxr0; xr1 = nxr1;
    }
  }
}

// ---------- per-iteration: CSR gather + GRU, fused (proven R11;
// quarter-major msg gather) ----------
__global__ __launch_bounds__(512) void node_kernel(
    float* __restrict__ x, const float* __restrict__ msg,
    const int* __restrict__ off, const int* __restrict__ inc,
    const float* __restrict__ W_ih, const float* __restrict__ W_hh,
    const float* __restrict__ b_ih, const float* __restrict__ b_hh) {
  __shared__ float wih[64 * 97];   // wih[k*97+q] = W_ih[q][k]
  __shared__ float whh[32 * 97];
  __shared__ float xs[16][32], ms[16][32];
  int t = threadIdx.x;
  for (int p = t; p < 6144; p += 512) {
    int q = p >> 6, k = p & 63;
    wih[k * 97 + q] = W_ih[p];
  }
  for (int p = t; p < 3072; p += 512) {
    int q = p >> 5, k = p & 31;
    whh[k * 97 + q] = W_hh[p];
  }
  int slot = t >> 5, i = t & 31;
  int n = blockIdx.x * 16 + slot;   // 3125*16 = 50000 exact
  float xv = x[(size_t)n * 32 + i];
  xs[slot][i] = xv;
  float acc = 0.f;
  int s0 = off[n], s1 = off[n + 1];
  const float* msgq = msg + (size_t)(i >> 3) * N_EDGES * 8 + (i & 7);
  for (int k = s0; k < s1; k++) {
    int e = inc[k];
    acc += msgq[(size_t)e * 8];
  }
  ms[slot][i] = acc;
  __syncthreads();

  float gir = b_ih[i], giz = b_ih[32 + i], gin = b_ih[64 + i];
  float ghr = b_hh[i], ghz = b_hh[32 + i], ghn = b_hh[64 + i];
#pragma unroll 4
  for (int k = 0; k < 32; k++) {
    float xk = xs[slot][k];
    float mk = ms[slot][k];
    const float* wa = &wih[k * 97];          // W_ih[.][k]     (x part)
    const float* wb = &wih[(32 + k) * 97];   // W_ih[.][32+k]  (m part)
    gir += xk * wa[i] + mk * wb[i];
    giz += xk * wa[32 + i] + mk * wb[32 + i];
    gin += xk * wa[64 + i] + mk * wb[64 + i];
    const float* hc = &whh[k * 97];
    ghr += xk * hc[i];
    ghz += xk * hc[32 + i];
    ghn += xk * hc[64 + i];
  }
  float r = 1.f / (1.f + __expf(-(gir + ghr)));
  float z = 1.f / (1.f + __expf(-(giz + ghz)));
  float nn = tanhf(gin + r * ghn);
  x[(size_t)n * 32 + i] = (1.f - z) * nn + z * xv;
}

__global__ void copy4_kernel(float4* __restrict__ dst, const float4* __restrict__ src, int n4) {
  int i = blockIdx.x * blockDim.x + threadIdx.x;
  if (i < n4) dst[i] = src[i];
}

extern "C" void kernel_launch(void* const* d_in, const int* in_sizes, int n_in,
                              void* d_out, int out_size, void* d_ws, size_t ws_size,
                              hipStream_t stream) {
  const float* x_in      = (const float*)d_in[0];
  const float* edge_data = (const float*)d_in[1];
  const int*   edges     = (const int*)d_in[2];
  // d_in[3] = T (always 8; hard-coded)
  const float* W1   = (const float*)d_in[4];
  const float* b1   = (const float*)d_in[5];
  const float* W2   = (const float*)d_in[6];
  const float* b2   = (const float*)d_in[7];
  const float* W_ih = (const float*)d_in[8];
  const float* W_hh = (const float*)d_in[9];
  const float* b_ih = (const float*)d_in[10];
  const float* b_hh = (const float*)d_in[11];

  // Workspace 79.06 MB (< 83.59 MB proven bound from R9's nChunks==1):
  // hidh 25.6M | hidl 25.6M | W2Fh 128K | W2Fl 128K | inc 1.6M | off | cur | msg 25.6M
  char* ws = (char*)d_ws;
  size_t o = 0;
  uint32_t* hidh = (uint32_t*)(ws + o); o += (size_t)N_EDGES * 64 * 2;
  uint32_t* hidl = (uint32_t*)(ws + o); o += (size_t)N_EDGES * 64 * 2;
  uint32_t* W2Fh = (uint32_t*)(ws + o); o += 32768u * 4;
  uint32_t* W2Fl = (uint32_t*)(ws + o); o += 32768u * 4;
  int*      inc  = (int*)(ws + o);      o += (size_t)2 * N_EDGES * 4;
  int*      off  = (int*)(ws + o);      o += (size_t)(N_NODES + 4) * 4;
  int*      cur  = (int*)(ws + o);      o += (size_t)N_NODES * 4;
  float*    msg  = (float*)(ws + o);    o += (size_t)N_EDGES * 32 * 4;
  float*    x    = (float*)d_out;   // iterate x in-place in d_out

  const int n4x = N_NODES * H / 4;  // 400000
  copy4_kernel<<<(n4x + 255) / 256, 256, 0, stream>>>((float4*)x, (const float4*)x_in, n4x);
  hidb_kernel<<<N_EDGES * 32 / 256, 256, 0, stream>>>(edge_data, W1, b1, hidh, hidl);
  w2pack_kernel<<<32768 / 256, 256, 0, stream>>>(W2, W2Fh, W2Fl);

  zero_cur_kernel<<<(N_NODES + 255) / 256, 256, 0, stream>>>(cur);
  count_kernel<<<(N_EDGES + 255) / 256, 256, 0, stream>>>(edges, cur);
  scan_kernel<<<1, 1024, 0, stream>>>(cur, off);
  scatter_kernel<<<(N_EDGES + 255) / 256, 256, 0, stream>>>(edges, cur, inc);

  for (int it = 0; it < T_STEPS; it++) {
    msg_kernel<<<1024, 256, 0, stream>>>(W2Fh, W2Fl, hidh, hidl, b2, x, edges, msg);
    node_kernel<<<N_NODES / 16, 512, 0, stream>>>(x, msg, off, inc,
                                                  W_ih, W_hh, b_ih, b_hh);
  }
}

// Round 4
// 1803.357 us; speedup vs baseline: 2.0119x; 2.0119x over previous
//
#include <hip/hip_runtime.h>
#include <stdint.h>

#define N_NODES 50000
#define N_EDGES 200000
#define H 32
#define T_STEPS 8
#define NGROUPS (N_EDGES / 64)   // 3125, exact: no tail handling anywhere

typedef __attribute__((ext_vector_type(4))) float v4f;
typedef __attribute__((ext_vector_type(8))) _Float16 h8;

#define LO_SCALE 4096.0f
#define LO_DESCALE 2.44140625e-4f  // 1/4096

__device__ __forceinline__ uint32_t packh2(_Float16 a, _Float16 b) {
  return (uint32_t)__builtin_bit_cast(unsigned short, a) |
         ((uint32_t)__builtin_bit_cast(unsigned short, b) << 16);
}

// hid[e][d] = relu(edge_data[e].W1[d] + b1[d]), fp16 hi + scaled-lo. (proven)
__global__ void hidb_kernel(const float* __restrict__ ed, const float* __restrict__ W1,
                            const float* __restrict__ b1,
                            uint32_t* __restrict__ hidh, uint32_t* __restrict__ hidl) {
  int idx = blockIdx.x * blockDim.x + threadIdx.x;   // E*32 threads
  int e = idx >> 5, d2 = idx & 31;
  int d0 = d2 * 2;
  const float4* er = (const float4*)(ed + (size_t)e * 16);
  const float4* w0 = (const float4*)(W1 + (size_t)d0 * 16);
  const float4* w1 = (const float4*)(W1 + (size_t)(d0 + 1) * 16);
  float a0 = b1[d0], a1 = b1[d0 + 1];
#pragma unroll
  for (int k = 0; k < 4; k++) {
    float4 h = er[k], u = w0[k], v = w1[k];
    a0 += h.x * u.x + h.y * u.y + h.z * u.z + h.w * u.w;
    a1 += h.x * v.x + h.y * v.y + h.z * v.z + h.w * v.w;
  }
  a0 = fmaxf(a0, 0.f);
  a1 = fmaxf(a1, 0.f);
  _Float16 h0 = (_Float16)a0, h1 = (_Float16)a1;
  _Float16 l0 = (_Float16)((a0 - (float)h0) * LO_SCALE);
  _Float16 l1 = (_Float16)((a1 - (float)h1) * LO_SCALE);
  hidh[idx] = packh2(h0, h1);
  hidl[idx] = packh2(l0, l1);
}

// Pack W2 into MFMA A-fragment-linear fp16 hi / scaled-lo. (proven)
__global__ void w2pack_kernel(const float* __restrict__ W2,
                              uint32_t* __restrict__ W2Fh, uint32_t* __restrict__ W2Fl) {
  int o = blockIdx.x * blockDim.x + threadIdx.x;   // 32768 threads
  int c = o >> 8, u = o & 255;
  int lane = u >> 2, pr = u & 3;
  int mtg = c >> 1, kh = c & 1;
  int row = mtg * 16 + (lane & 15);
  int k = kh * 32 + (lane >> 4) * 8 + pr * 2;
  float v0 = W2[(size_t)row * 64 + k];
  float v1 = W2[(size_t)row * 64 + k + 1];
  _Float16 h0 = (_Float16)v0, h1 = (_Float16)v1;
  _Float16 l0 = (_Float16)((v0 - (float)h0) * LO_SCALE);
  _Float16 l1 = (_Float16)((v1 - (float)h1) * LO_SCALE);
  W2Fh[o] = packh2(h0, h1);
  W2Fl[o] = packh2(l0, l1);
}

// ---------- CSR incidence build (proven R11) ----------
__global__ void zero_cur_kernel(int* __restrict__ cur) {
  int i = blockIdx.x * blockDim.x + threadIdx.x;
  if (i < N_NODES) cur[i] = 0;
}
__global__ void count_kernel(const int* __restrict__ edges, int* __restrict__ cur) {
  int e = blockIdx.x * blockDim.x + threadIdx.x;
  if (e < N_EDGES) {
    int s = edges[2 * e], d = edges[2 * e + 1];
    atomicAdd(&cur[s], 1);
    if (d != s) atomicAdd(&cur[d], 1);
  }
}
__global__ __launch_bounds__(1024) void scan_kernel(int* __restrict__ cur,
                                                    int* __restrict__ off) {
  __shared__ int lds[1024];
  int t = threadIdx.x;
  int base = t * 49;
  int cnt = 0;
  for (int j = 0; j < 49; j++) {
    int idx = base + j;
    if (idx < N_NODES) cnt += cur[idx];
  }
  lds[t] = cnt;
  __syncthreads();
  for (int d = 1; d < 1024; d <<= 1) {
    int v = (t >= d) ? lds[t - d] : 0;
    __syncthreads();
    lds[t] += v;
    __syncthreads();
  }
  int run = lds[t] - cnt;   // exclusive prefix of this thread's chunk
  for (int j = 0; j < 49; j++) {
    int idx = base + j;
    if (idx < N_NODES) {
      int c = cur[idx];
      off[idx] = run;
      cur[idx] = run;
      run += c;
    }
  }
  if (t == 1023) off[N_NODES] = lds[1023];
}
__global__ void scatter_kernel(const int* __restrict__ edges, int* __restrict__ cur,
                               int* __restrict__ inc) {
  int e = blockIdx.x * blockDim.x + threadIdx.x;
  if (e < N_EDGES) {
    int s = edges[2 * e], d = edges[2 * e + 1];
    int p = atomicAdd(&cur[s], 1);
    inc[p] = e;
    if (d != s) {
      p = atomicAdd(&cur[d], 1);
      inc[p] = e;
    }
  }
}

// ---------- async global->LDS helper (zero VGPR staging) ----------
typedef __attribute__((address_space(1))) const uint32_t gq_u32;
typedef __attribute__((address_space(3))) uint32_t lds_q_u32;
__device__ __forceinline__ void gload_lds16(const uint32_t* g, uint32_t* l) {
  // lds dst: wave-uniform base + lane*16B (hardware); global src per-lane.
  __builtin_amdgcn_global_load_lds((gq_u32*)g, (lds_q_u32*)l, 16, 0, 0);
}

// Stage one W2F eighth (16KB hi + 16KB lo) into LDS buffers bh/bl.
// 4 waves x 4 calls x (64 lanes x 16B) = 16KB per array.
__device__ __forceinline__ void stage_eighth(const uint32_t* __restrict__ W2Fh,
                                             const uint32_t* __restrict__ W2Fl,
                                             uint32_t* bh, uint32_t* bl,
                                             int eighth, int wv, int lane) {
#pragma unroll
  for (int k = 0; k < 4; k++) {
    int ub = (wv * 4 + k) * 256;          // wave-uniform lds base (uint32 units)
    int u  = ub + lane * 4;               // per-lane global index (16B per lane)
    gload_lds16(W2Fh + eighth * 4096 + u, bh + ub);
    gload_lds16(W2Fl + eighth * 4096 + u, bl + ub);
  }
}

// ---------- message build R4: full-row per block, W2 streamed through LDS ----
// R3 post-mortem: duration tracks fetch bytes linearly (~3.75 TB/s effective)
// -> traffic-bound, not latency-bound. The 4x amplification (each edge's hid/x
// fetched by 4 mq-quarter blocks) is the target.
// New: ONE block computes all 32 msg dims per edge. The 4 W2 quarters can't
// be LDS-resident (256KB), so they STREAM: per edge-group, loop 8 eighths
// (16KB hi+16KB lo), double-buffered via global_load_lds (T3 pattern: issue
// next eighth -> compute current -> barrier). W2F re-reads come from L2
// (256KB unique, resident per XCD). hid/x/edges now read ONCE globally.
// Inner MFMA math verbatim R0; per-stage output dims i = q*8+h*4+mp2
// (algebra: W2 row = q*256+h*128+(2*mp2+tp)*16+kg*4+r -> i=row>>5, j=row&31).
// msg is EDGE-MAJOR msg[e][32]: safe now, block owns the full 128B row
// (no cross-block line sharing). Blocks take contiguous group ranges: hid
// streams sequentially, each line fetched once machine-wide.
// LDS 68KB -> 2 blocks/CU (unchanged); no hid/x prefetch rotation (R3 lesson).
__global__ __launch_bounds__(256, 2) void msg_kernel(
    const uint32_t* __restrict__ W2Fh, const uint32_t* __restrict__ W2Fl,
    const uint32_t* __restrict__ hidh, const uint32_t* __restrict__ hidl,
    const float* __restrict__ b2, const float* __restrict__ x,
    const int* __restrict__ edges, float* __restrict__ msg) {
  __shared__ uint32_t w2h[2][4096];   // 2 x 16KB: eighth double-buffer, hi
  __shared__ uint32_t w2l[2][4096];   // 2 x 16KB: scaled lo
  __shared__ float b2s[1024];
  int t = threadIdx.x;
  int bid = blockIdx.x;
  // contiguous group range per block: grid 512 (exactly resident at 2/CU)
  int gs = (int)(((long)bid * NGROUPS) >> 9);
  int ge = (int)(((long)(bid + 1) * NGROUPS) >> 9);
  int wv = t >> 6, lane = t & 63;
  int el = lane & 15, kg = lane >> 4;

  for (int i = t; i < 1024; i += 256) b2s[i] = b2[i];
  // prologue: stage eighth 0 into buffer 0
  stage_eighth(W2Fh, W2Fl, w2h[0], w2l[0], 0, wv, lane);
  __syncthreads();

  const h8* hbh = (const h8*)hidh;
  const h8* hbl = (const h8*)hidl;
  int cb = 0;

  for (int g = gs; g < ge; ++g) {
    int e = g * 64 + wv * 16 + el;          // < 200000 always (3125*64 exact)
    int src = edges[2 * e];
    h8 bh0 = hbh[(size_t)e * 8 + kg];
    h8 bh1 = hbh[(size_t)e * 8 + 4 + kg];
    h8 bl0 = hbl[(size_t)e * 8 + kg];
    h8 bl1 = hbl[(size_t)e * 8 + 4 + kg];
    v4f xr0 = *(const v4f*)(x + (size_t)src * 32 + kg * 4);
    v4f xr1 = *(const v4f*)(x + (size_t)src * 32 + 16 + kg * 4);

    for (int s = 0; s < 8; ++s) {
      // issue next eighth's async staging into the other buffer
      if (!(s == 7 && g == ge - 1)) {
        stage_eighth(W2Fh, W2Fl, w2h[cb ^ 1], w2l[cb ^ 1], (s + 1) & 7, wv, lane);
      }
      int q = s >> 1, h = s & 1;
      const h8* sh = (const h8*)w2h[cb];
      const h8* sl = (const h8*)w2l[cb];
      const float* b2p = b2s + q * 256 + h * 128 + kg * 4;

      float sacc[4];
#pragma unroll
      for (int mp2 = 0; mp2 < 4; mp2++) {
        float tacc = 0.f;
#pragma unroll
        for (int tp = 0; tp < 2; tp++) {
          int lm = 2 * mp2 + tp;   // within-eighth M-tile, 0..7
          h8 ah0 = sh[(size_t)(lm * 2 + 0) * 64 + lane];
          h8 ah1 = sh[(size_t)(lm * 2 + 1) * 64 + lane];
          h8 al0 = sl[(size_t)(lm * 2 + 0) * 64 + lane];
          h8 al1 = sl[(size_t)(lm * 2 + 1) * 64 + lane];
          v4f chi = *(const v4f*)(b2p + lm * 16);   // bias as C-init
          chi = __builtin_amdgcn_mfma_f32_16x16x32_f16(ah0, bh0, chi, 0, 0, 0);
          chi = __builtin_amdgcn_mfma_f32_16x16x32_f16(ah1, bh1, chi, 0, 0, 0);
          v4f clo = {0.f, 0.f, 0.f, 0.f};
          clo = __builtin_amdgcn_mfma_f32_16x16x32_f16(ah0, bl0, clo, 0, 0, 0);
          clo = __builtin_amdgcn_mfma_f32_16x16x32_f16(ah1, bl1, clo, 0, 0, 0);
          clo = __builtin_amdgcn_mfma_f32_16x16x32_f16(al0, bh0, clo, 0, 0, 0);
          clo = __builtin_amdgcn_mfma_f32_16x16x32_f16(al1, bh1, clo, 0, 0, 0);
          v4f xr = tp ? xr1 : xr0;
#pragma unroll
          for (int r = 0; r < 4; r++) {
            float av = fmaxf(fmaf(clo[r], LO_DESCALE, chi[r]), 0.f);
            tacc = fmaf(av, xr[r], tacc);
          }
        }
        float sv = tacc;
        sv += __shfl_xor(sv, 16, 64);
        sv += __shfl_xor(sv, 32, 64);
        sacc[mp2] = sv;   // msg value for (e, i = q*8 + h*4 + mp2)
      }
      if (lane < 16) {
        v4f sv4 = {sacc[0], sacc[1], sacc[2], sacc[3]};
        *(v4f*)(msg + (size_t)e * 32 + q * 8 + h * 4) = sv4;
      }
      __syncthreads();   // drains global_load_lds (vmcnt) + LDS ops
      cb ^= 1;
    }
  }
}

// ---------- per-iteration: CSR gather + GRU, fused (proven R11; gather
// adapted to edge-major msg: one 128B line per incident edge) ----------
__global__ __launch_bounds__(512) void node_kernel(
    float* __restrict__ x, const float* __restrict__ msg,
    const int* __restrict__ off, const int* __restrict__ inc,
    const float* __restrict__ W_ih, const float* __restrict__ W_hh,
    const float* __restrict__ b_ih, const float* __restrict__ b_hh) {
  __shared__ float wih[64 * 97];   // wih[k*97+q] = W_ih[q][k]
  __shared__ float whh[32 * 97];
  __shared__ float xs[16][32], ms[16][32];
  int t = threadIdx.x;
  for (int p = t; p < 6144; p += 512) {
    int q = p >> 6, k = p & 63;
    wih[k * 97 + q] = W_ih[p];
  }
  for (int p = t; p < 3072; p += 512) {
    int q = p >> 5, k = p & 31;
    whh[k * 97 + q] = W_hh[p];
  }
  int slot = t >> 5, i = t & 31;
  int n = blockIdx.x * 16 + slot;   // 3125*16 = 50000 exact
  float xv = x[(size_t)n * 32 + i];
  xs[slot][i] = xv;
  float acc = 0.f;
  int s0 = off[n], s1 = off[n + 1];
  for (int k = s0; k < s1; k++) {
    int e = inc[k];
    acc += msg[(size_t)e * 32 + i];   // edge-major: lanes 0..31 = one 128B line
  }
  ms[slot][i] = acc;
  __syncthreads();

  float gir = b_ih[i], giz = b_ih[32 + i], gin = b_ih[64 + i];
  float ghr = b_hh[i], ghz = b_hh[32 + i], ghn = b_hh[64 + i];
#pragma unroll 4
  for (int k = 0; k < 32; k++) {
    float xk = xs[slot][k];
    float mk = ms[slot][k];
    const float* wa = &wih[k * 97];          // W_ih[.][k]     (x part)
    const float* wb = &wih[(32 + k) * 97];   // W_ih[.][32+k]  (m part)
    gir += xk * wa[i] + mk * wb[i];
    giz += xk * wa[32 + i] + mk * wb[32 + i];
    gin += xk * wa[64 + i] + mk * wb[64 + i];
    const float* hc = &whh[k * 97];
    ghr += xk * hc[i];
    ghz += xk * hc[32 + i];
    ghn += xk * hc[64 + i];
  }
  float r = 1.f / (1.f + __expf(-(gir + ghr)));
  float z = 1.f / (1.f + __expf(-(giz + ghz)));
  float nn = tanhf(gin + r * ghn);
  x[(size_t)n * 32 + i] = (1.f - z) * nn + z * xv;
}

__global__ void copy4_kernel(float4* __restrict__ dst, const float4* __restrict__ src, int n4) {
  int i = blockIdx.x * blockDim.x + threadIdx.x;
  if (i < n4) dst[i] = src[i];
}

extern "C" void kernel_launch(void* const* d_in, const int* in_sizes, int n_in,
                              void* d_out, int out_size, void* d_ws, size_t ws_size,
                              hipStream_t stream) {
  const float* x_in      = (const float*)d_in[0];
  const float* edge_data = (const float*)d_in[1];
  const int*   edges     = (const int*)d_in[2];
  // d_in[3] = T (always 8; hard-coded)
  const float* W1   = (const float*)d_in[4];
  const float* b1   = (const float*)d_in[5];
  const float* W2   = (const float*)d_in[6];
  const float* b2   = (const float*)d_in[7];
  const float* W_ih = (const float*)d_in[8];
  const float* W_hh = (const float*)d_in[9];
  const float* b_ih = (const float*)d_in[10];
  const float* b_hh = (const float*)d_in[11];

  // Workspace 79.06 MB (< 83.59 MB proven bound):
  // hidh 25.6M | hidl 25.6M | W2Fh 128K | W2Fl 128K | inc 1.6M | off | cur | msg 25.6M
  char* ws = (char*)d_ws;
  size_t o = 0;
  uint32_t* hidh = (uint32_t*)(ws + o); o += (size_t)N_EDGES * 64 * 2;
  uint32_t* hidl = (uint32_t*)(ws + o); o += (size_t)N_EDGES * 64 * 2;
  uint32_t* W2Fh = (uint32_t*)(ws + o); o += 32768u * 4;
  uint32_t* W2Fl = (uint32_t*)(ws + o); o += 32768u * 4;
  int*      inc  = (int*)(ws + o);      o += (size_t)2 * N_EDGES * 4;
  int*      off  = (int*)(ws + o);      o += (size_t)(N_NODES + 4) * 4;
  int*      cur  = (int*)(ws + o);      o += (size_t)N_NODES * 4;
  float*    msg  = (float*)(ws + o);    o += (size_t)N_EDGES * 32 * 4;
  float*    x    = (float*)d_out;   // iterate x in-place in d_out

  const int n4x = N_NODES * H / 4;  // 400000
  copy4_kernel<<<(n4x + 255) / 256, 256, 0, stream>>>((float4*)x, (const float4*)x_in, n4x);
  hidb_kernel<<<N_EDGES * 32 / 256, 256, 0, stream>>>(edge_data, W1, b1, hidh, hidl);
  w2pack_kernel<<<32768 / 256, 256, 0, stream>>>(W2, W2Fh, W2Fl);

  zero_cur_kernel<<<(N_NODES + 255) / 256, 256, 0, stream>>>(cur);
  count_kernel<<<(N_EDGES + 255) / 256, 256, 0, stream>>>(edges, cur);
  scan_kernel<<<1, 1024, 0, stream>>>(cur, off);
  scatter_kernel<<<(N_EDGES + 255) / 256, 256, 0, stream>>>(edges, cur, inc);

  for (int it = 0; it < T_STEPS; it++) {
    msg_kernel<<<512, 256, 0, stream>>>(W2Fh, W2Fl, hidh, hidl, b2, x, edges, msg);
    node_kernel<<<N_NODES / 16, 512, 0, stream>>>(x, msg, off, inc,
                                                  W_ih, W_hh, b_ih, b_hh);
  }
}

// Round 5
// 1688.072 us; speedup vs baseline: 2.1493x; 1.0683x over previous
//
#include <hip/hip_runtime.h>
#include <stdint.h>

#define N_NODES 50000
#define N_EDGES 200000
#define H 32
#define T_STEPS 8
#define NGROUPS (N_EDGES / 64)   // 3125, exact: no tail handling anywhere

typedef __attribute__((ext_vector_type(4))) float v4f;
typedef __attribute__((ext_vector_type(8))) _Float16 h8;

#define LO_SCALE 4096.0f
#define LO_DESCALE 2.44140625e-4f  // 1/4096

__device__ __forceinline__ uint32_t packh2(_Float16 a, _Float16 b) {
  return (uint32_t)__builtin_bit_cast(unsigned short, a) |
         ((uint32_t)__builtin_bit_cast(unsigned short, b) << 16);
}

// hid[e][d] = relu(edge_data[e].W1[d] + b1[d]), fp16 hi + scaled-lo. (proven)
__global__ void hidb_kernel(const float* __restrict__ ed, const float* __restrict__ W1,
                            const float* __restrict__ b1,
                            uint32_t* __restrict__ hidh, uint32_t* __restrict__ hidl) {
  int idx = blockIdx.x * blockDim.x + threadIdx.x;   // E*32 threads
  int e = idx >> 5, d2 = idx & 31;
  int d0 = d2 * 2;
  const float4* er = (const float4*)(ed + (size_t)e * 16);
  const float4* w0 = (const float4*)(W1 + (size_t)d0 * 16);
  const float4* w1 = (const float4*)(W1 + (size_t)(d0 + 1) * 16);
  float a0 = b1[d0], a1 = b1[d0 + 1];
#pragma unroll
  for (int k = 0; k < 4; k++) {
    float4 h = er[k], u = w0[k], v = w1[k];
    a0 += h.x * u.x + h.y * u.y + h.z * u.z + h.w * u.w;
    a1 += h.x * v.x + h.y * v.y + h.z * v.z + h.w * v.w;
  }
  a0 = fmaxf(a0, 0.f);
  a1 = fmaxf(a1, 0.f);
  _Float16 h0 = (_Float16)a0, h1 = (_Float16)a1;
  _Float16 l0 = (_Float16)((a0 - (float)h0) * LO_SCALE);
  _Float16 l1 = (_Float16)((a1 - (float)h1) * LO_SCALE);
  hidh[idx] = packh2(h0, h1);
  hidl[idx] = packh2(l0, l1);
}

// Pack W2 into MFMA A-fragment-linear fp16 hi / scaled-lo. (proven)
__global__ void w2pack_kernel(const float* __restrict__ W2,
                              uint32_t* __restrict__ W2Fh, uint32_t* __restrict__ W2Fl) {
  int o = blockIdx.x * blockDim.x + threadIdx.x;   // 32768 threads
  int c = o >> 8, u = o & 255;
  int lane = u >> 2, pr = u & 3;
  int mtg = c >> 1, kh = c & 1;
  int row = mtg * 16 + (lane & 15);
  int k = kh * 32 + (lane >> 4) * 8 + pr * 2;
  float v0 = W2[(size_t)row * 64 + k];
  float v1 = W2[(size_t)row * 64 + k + 1];
  _Float16 h0 = (_Float16)v0, h1 = (_Float16)v1;
  _Float16 l0 = (_Float16)((v0 - (float)h0) * LO_SCALE);
  _Float16 l1 = (_Float16)((v1 - (float)h1) * LO_SCALE);
  W2Fh[o] = packh2(h0, h1);
  W2Fl[o] = packh2(l0, l1);
}

// ---------- CSR incidence build (proven R11) ----------
__global__ void zero_cur_kernel(int* __restrict__ cur) {
  int i = blockIdx.x * blockDim.x + threadIdx.x;
  if (i < N_NODES) cur[i] = 0;
}
__global__ void count_kernel(const int* __restrict__ edges, int* __restrict__ cur) {
  int e = blockIdx.x * blockDim.x + threadIdx.x;
  if (e < N_EDGES) {
    int s = edges[2 * e], d = edges[2 * e + 1];
    atomicAdd(&cur[s], 1);
    if (d != s) atomicAdd(&cur[d], 1);
  }
}
__global__ __launch_bounds__(1024) void scan_kernel(int* __restrict__ cur,
                                                    int* __restrict__ off) {
  __shared__ int lds[1024];
  int t = threadIdx.x;
  int base = t * 49;
  int cnt = 0;
  for (int j = 0; j < 49; j++) {
    int idx = base + j;
    if (idx < N_NODES) cnt += cur[idx];
  }
  lds[t] = cnt;
  __syncthreads();
  for (int d = 1; d < 1024; d <<= 1) {
    int v = (t >= d) ? lds[t - d] : 0;
    __syncthreads();
    lds[t] += v;
    __syncthreads();
  }
  int run = lds[t] - cnt;   // exclusive prefix of this thread's chunk
  for (int j = 0; j < 49; j++) {
    int idx = base + j;
    if (idx < N_NODES) {
      int c = cur[idx];
      off[idx] = run;
      cur[idx] = run;
      run += c;
    }
  }
  if (t == 1023) off[N_NODES] = lds[1023];
}
__global__ void scatter_kernel(const int* __restrict__ edges, int* __restrict__ cur,
                               int* __restrict__ inc) {
  int e = blockIdx.x * blockDim.x + threadIdx.x;
  if (e < N_EDGES) {
    int s = edges[2 * e], d = edges[2 * e + 1];
    int p = atomicAdd(&cur[s], 1);
    inc[p] = e;
    if (d != s) {
      p = atomicAdd(&cur[d], 1);
      inc[p] = e;
    }
  }
}

// ---------- async global->LDS helper (zero VGPR staging) ----------
typedef __attribute__((address_space(1))) const uint32_t gq_u32;
typedef __attribute__((address_space(3))) uint32_t lds_q_u32;
__device__ __forceinline__ void gload_lds16(const uint32_t* g, uint32_t* l) {
  // lds dst: wave-uniform base + lane*16B (hardware); global src per-lane.
  __builtin_amdgcn_global_load_lds((gq_u32*)g, (lds_q_u32*)l, 16, 0, 0);
}

// Stage one W2F eighth (16KB hi + 16KB lo) into LDS buffers bh/bl.
// 4 waves x 4 calls x (64 lanes x 16B) = 16KB per array.
__device__ __forceinline__ void stage_eighth(const uint32_t* __restrict__ W2Fh,
                                             const uint32_t* __restrict__ W2Fl,
                                             uint32_t* bh, uint32_t* bl,
                                             int eighth, int wv, int lane) {
#pragma unroll
  for (int k = 0; k < 4; k++) {
    int ub = (wv * 4 + k) * 256;          // wave-uniform lds base (uint32 units)
    int u  = ub + lane * 4;               // per-lane global index (16B per lane)
    gload_lds16(W2Fh + eighth * 4096 + u, bh + ub);
    gload_lds16(W2Fl + eighth * 4096 + u, bl + ub);
  }
}

// ---------- message build R5: R4 structure + 2 edge-groups per W2 pass ----
// R4 post-mortem: traffic collapsed (FETCH 894->45MB), total 3227->1803.
// Remaining msg cost model: per stage each wave did 32 ds_read_b128 to feed
// 48 MFMAs for only 16 edges -> ~62us of LDS-read serialization per dispatch
// is the binding pipe. This round: amortize each W2 fragment read over TWO
// edge-groups (128 edges per stream pass) -> 12 MFMAs per fragment read,
// LDS-read pressure per edge halves, W2F L2 re-reads and barriers halve.
// Odd group-count tail: set B duplicates set A, store suppressed.
// All MFMA math / fragment algebra / staging / msg layout verbatim R4.
// VGPR ~88 -> ~140 (fine: 2 waves/SIMD => 256 budget; occupancy LDS-capped).
__global__ __launch_bounds__(256, 2) void msg_kernel(
    const uint32_t* __restrict__ W2Fh, const uint32_t* __restrict__ W2Fl,
    const uint32_t* __restrict__ hidh, const uint32_t* __restrict__ hidl,
    const float* __restrict__ b2, const float* __restrict__ x,
    const int* __restrict__ edges, float* __restrict__ msg) {
  __shared__ uint32_t w2h[2][4096];   // 2 x 16KB: eighth double-buffer, hi
  __shared__ uint32_t w2l[2][4096];   // 2 x 16KB: scaled lo
  __shared__ float b2s[1024];
  int t = threadIdx.x;
  int bid = blockIdx.x;
  // contiguous group range per block: grid 512 (exactly resident at 2/CU)
  int gs = (int)(((long)bid * NGROUPS) >> 9);
  int ge = (int)(((long)(bid + 1) * NGROUPS) >> 9);
  int wv = t >> 6, lane = t & 63;
  int el = lane & 15, kg = lane >> 4;

  for (int i = t; i < 1024; i += 256) b2s[i] = b2[i];
  // prologue: stage eighth 0 into buffer 0
  stage_eighth(W2Fh, W2Fl, w2h[0], w2l[0], 0, wv, lane);
  __syncthreads();

  const h8* hbh = (const h8*)hidh;
  const h8* hbl = (const h8*)hidl;
  int cb = 0;

  for (int g = gs; g < ge; g += 2) {
    bool two = (g + 1 < ge);
    int gB = two ? g + 1 : g;               // duplicate compute on odd tail
    int eA = g  * 64 + wv * 16 + el;        // < 200000 always (3125*64 exact)
    int eB = gB * 64 + wv * 16 + el;
    int srcA = edges[2 * eA];
    int srcB = edges[2 * eB];
    h8 Abh0 = hbh[(size_t)eA * 8 + kg];
    h8 Abh1 = hbh[(size_t)eA * 8 + 4 + kg];
    h8 Abl0 = hbl[(size_t)eA * 8 + kg];
    h8 Abl1 = hbl[(size_t)eA * 8 + 4 + kg];
    h8 Bbh0 = hbh[(size_t)eB * 8 + kg];
    h8 Bbh1 = hbh[(size_t)eB * 8 + 4 + kg];
    h8 Bbl0 = hbl[(size_t)eB * 8 + kg];
    h8 Bbl1 = hbl[(size_t)eB * 8 + 4 + kg];
    v4f AxR0 = *(const v4f*)(x + (size_t)srcA * 32 + kg * 4);
    v4f AxR1 = *(const v4f*)(x + (size_t)srcA * 32 + 16 + kg * 4);
    v4f BxR0 = *(const v4f*)(x + (size_t)srcB * 32 + kg * 4);
    v4f BxR1 = *(const v4f*)(x + (size_t)srcB * 32 + 16 + kg * 4);

    for (int s = 0; s < 8; ++s) {
      // issue next eighth's async staging into the other buffer
      if (!(s == 7 && g + 2 >= ge)) {
        stage_eighth(W2Fh, W2Fl, w2h[cb ^ 1], w2l[cb ^ 1], (s + 1) & 7, wv, lane);
      }
      int q = s >> 1, h = s & 1;
      const h8* sh = (const h8*)w2h[cb];
      const h8* sl = (const h8*)w2l[cb];
      const float* b2p = b2s + q * 256 + h * 128 + kg * 4;

      float saccA[4], saccB[4];
#pragma unroll
      for (int mp2 = 0; mp2 < 4; mp2++) {
        float tA = 0.f, tB = 0.f;
#pragma unroll
        for (int tp = 0; tp < 2; tp++) {
          int lm = 2 * mp2 + tp;   // within-eighth M-tile, 0..7
          h8 ah0 = sh[(size_t)(lm * 2 + 0) * 64 + lane];
          h8 ah1 = sh[(size_t)(lm * 2 + 1) * 64 + lane];
          h8 al0 = sl[(size_t)(lm * 2 + 0) * 64 + lane];
          h8 al1 = sl[(size_t)(lm * 2 + 1) * 64 + lane];
          v4f bias = *(const v4f*)(b2p + lm * 16);
          // ---- edge-set A ----
          v4f chi = bias;
          chi = __builtin_amdgcn_mfma_f32_16x16x32_f16(ah0, Abh0, chi, 0, 0, 0);
          chi = __builtin_amdgcn_mfma_f32_16x16x32_f16(ah1, Abh1, chi, 0, 0, 0);
          v4f clo = {0.f, 0.f, 0.f, 0.f};
          clo = __builtin_amdgcn_mfma_f32_16x16x32_f16(ah0, Abl0, clo, 0, 0, 0);
          clo = __builtin_amdgcn_mfma_f32_16x16x32_f16(ah1, Abl1, clo, 0, 0, 0);
          clo = __builtin_amdgcn_mfma_f32_16x16x32_f16(al0, Abh0, clo, 0, 0, 0);
          clo = __builtin_amdgcn_mfma_f32_16x16x32_f16(al1, Abh1, clo, 0, 0, 0);
          v4f xrA = tp ? AxR1 : AxR0;
#pragma unroll
          for (int r = 0; r < 4; r++) {
            float av = fmaxf(fmaf(clo[r], LO_DESCALE, chi[r]), 0.f);
            tA = fmaf(av, xrA[r], tA);
          }
          // ---- edge-set B (same fragments) ----
          v4f chiB = bias;
          chiB = __builtin_amdgcn_mfma_f32_16x16x32_f16(ah0, Bbh0, chiB, 0, 0, 0);
          chiB = __builtin_amdgcn_mfma_f32_16x16x32_f16(ah1, Bbh1, chiB, 0, 0, 0);
          v4f cloB = {0.f, 0.f, 0.f, 0.f};
          cloB = __builtin_amdgcn_mfma_f32_16x16x32_f16(ah0, Bbl0, cloB, 0, 0, 0);
          cloB = __builtin_amdgcn_mfma_f32_16x16x32_f16(ah1, Bbl1, cloB, 0, 0, 0);
          cloB = __builtin_amdgcn_mfma_f32_16x16x32_f16(al0, Bbh0, cloB, 0, 0, 0);
          cloB = __builtin_amdgcn_mfma_f32_16x16x32_f16(al1, Bbh1, cloB, 0, 0, 0);
          v4f xrB = tp ? BxR1 : BxR0;
#pragma unroll
          for (int r = 0; r < 4; r++) {
            float av = fmaxf(fmaf(cloB[r], LO_DESCALE, chiB[r]), 0.f);
            tB = fmaf(av, xrB[r], tB);
          }
        }
        float sv = tA;
        sv += __shfl_xor(sv, 16, 64);
        sv += __shfl_xor(sv, 32, 64);
        saccA[mp2] = sv;   // msg value for (eA, i = q*8 + h*4 + mp2)
        sv = tB;
        sv += __shfl_xor(sv, 16, 64);
        sv += __shfl_xor(sv, 32, 64);
        saccB[mp2] = sv;
      }
      if (lane < 16) {
        v4f svA = {saccA[0], saccA[1], saccA[2], saccA[3]};
        *(v4f*)(msg + (size_t)eA * 32 + q * 8 + h * 4) = svA;
        if (two) {
          v4f svB = {saccB[0], saccB[1], saccB[2], saccB[3]};
          *(v4f*)(msg + (size_t)eB * 32 + q * 8 + h * 4) = svB;
        }
      }
      __syncthreads();   // drains global_load_lds (vmcnt) + LDS ops
      cb ^= 1;
    }
  }
}

// ---------- per-iteration: CSR gather + GRU, fused (proven R11; gather
// adapted to edge-major msg: one 128B line per incident edge) ----------
__global__ __launch_bounds__(512) void node_kernel(
    float* __restrict__ x, const float* __restrict__ msg,
    const int* __restrict__ off, const int* __restrict__ inc,
    const float* __restrict__ W_ih, const float* __restrict__ W_hh,
    const float* __restrict__ b_ih, const float* __restrict__ b_hh) {
  __shared__ float wih[64 * 97];   // wih[k*97+q] = W_ih[q][k]
  __shared__ float whh[32 * 97];
  __shared__ float xs[16][32], ms[16][32];
  int t = threadIdx.x;
  for (int p = t; p < 6144; p += 512) {
    int q = p >> 6, k = p & 63;
    wih[k * 97 + q] = W_ih[p];
  }
  for (int p = t; p < 3072; p += 512) {
    int q = p >> 5, k = p & 31;
    whh[k * 97 + q] = W_hh[p];
  }
  int slot = t >> 5, i = t & 31;
  int n = blockIdx.x * 16 + slot;   // 3125*16 = 50000 exact
  float xv = x[(size_t)n * 32 + i];
  xs[slot][i] = xv;
  float acc = 0.f;
  int s0 = off[n], s1 = off[n + 1];
  for (int k = s0; k < s1; k++) {
    int e = inc[k];
    acc += msg[(size_t)e * 32 + i];   // edge-major: lanes 0..31 = one 128B line
  }
  ms[slot][i] = acc;
  __syncthreads();

  float gir = b_ih[i], giz = b_ih[32 + i], gin = b_ih[64 + i];
  float ghr = b_hh[i], ghz = b_hh[32 + i], ghn = b_hh[64 + i];
#pragma unroll 4
  for (int k = 0; k < 32; k++) {
    float xk = xs[slot][k];
    float mk = ms[slot][k];
    const float* wa = &wih[k * 97];          // W_ih[.][k]     (x part)
    const float* wb = &wih[(32 + k) * 97];   // W_ih[.][32+k]  (m part)
    gir += xk * wa[i] + mk * wb[i];
    giz += xk * wa[32 + i] + mk * wb[32 + i];
    gin += xk * wa[64 + i] + mk * wb[64 + i];
    const float* hc = &whh[k * 97];
    ghr += xk * hc[i];
    ghz += xk * hc[32 + i];
    ghn += xk * hc[64 + i];
  }
  float r = 1.f / (1.f + __expf(-(gir + ghr)));
  float z = 1.f / (1.f + __expf(-(giz + ghz)));
  float nn = tanhf(gin + r * ghn);
  x[(size_t)n * 32 + i] = (1.f - z) * nn + z * xv;
}

__global__ void copy4_kernel(float4* __restrict__ dst, const float4* __restrict__ src, int n4) {
  int i = blockIdx.x * blockDim.x + threadIdx.x;
  if (i < n4) dst[i] = src[i];
}

extern "C" void kernel_launch(void* const* d_in, const int* in_sizes, int n_in,
                              void* d_out, int out_size, void* d_ws, size_t ws_size,
                              hipStream_t stream) {
  const float* x_in      = (const float*)d_in[0];
  const float* edge_data = (const float*)d_in[1];
  const int*   edges     = (const int*)d_in[2];
  // d_in[3] = T (always 8; hard-coded)
  const float* W1   = (const float*)d_in[4];
  const float* b1   = (const float*)d_in[5];
  const float* W2   = (const float*)d_in[6];
  const float* b2   = (const float*)d_in[7];
  const float* W_ih = (const float*)d_in[8];
  const float* W_hh = (const float*)d_in[9];
  const float* b_ih = (const float*)d_in[10];
  const float* b_hh = (const float*)d_in[11];

  // Workspace 79.06 MB (< 83.59 MB proven bound):
  // hidh 25.6M | hidl 25.6M | W2Fh 128K | W2Fl 128K | inc 1.6M | off | cur | msg 25.6M
  char* ws = (char*)d_ws;
  size_t o = 0;
  uint32_t* hidh = (uint32_t*)(ws + o); o += (size_t)N_EDGES * 64 * 2;
  uint32_t* hidl = (uint32_t*)(ws + o); o += (size_t)N_EDGES * 64 * 2;
  uint32_t* W2Fh = (uint32_t*)(ws + o); o += 32768u * 4;
  uint32_t* W2Fl = (uint32_t*)(ws + o); o += 32768u * 4;
  int*      inc  = (int*)(ws + o);      o += (size_t)2 * N_EDGES * 4;
  int*      off  = (int*)(ws + o);      o += (size_t)(N_NODES + 4) * 4;
  int*      cur  = (int*)(ws + o);      o += (size_t)N_NODES * 4;
  float*    msg  = (float*)(ws + o);    o += (size_t)N_EDGES * 32 * 4;
  float*    x    = (float*)d_out;   // iterate x in-place in d_out

  const int n4x = N_NODES * H / 4;  // 400000
  copy4_kernel<<<(n4x + 255) / 256, 256, 0, stream>>>((float4*)x, (const float4*)x_in, n4x);
  hidb_kernel<<<N_EDGES * 32 / 256, 256, 0, stream>>>(edge_data, W1, b1, hidh, hidl);
  w2pack_kernel<<<32768 / 256, 256, 0, stream>>>(W2, W2Fh, W2Fl);

  zero_cur_kernel<<<(N_NODES + 255) / 256, 256, 0, stream>>>(cur);
  count_kernel<<<(N_EDGES + 255) / 256, 256, 0, stream>>>(edges, cur);
  scan_kernel<<<1, 1024, 0, stream>>>(cur, off);
  scatter_kernel<<<(N_EDGES + 255) / 256, 256, 0, stream>>>(edges, cur, inc);

  for (int it = 0; it < T_STEPS; it++) {
    msg_kernel<<<512, 256, 0, stream>>>(W2Fh, W2Fl, hidh, hidl, b2, x, edges, msg);
    node_kernel<<<N_NODES / 16, 512, 0, stream>>>(x, msg, off, inc,
                                                  W_ih, W_hh, b_ih, b_hh);
  }
}

// Round 6
// 1593.450 us; speedup vs baseline: 2.2769x; 1.0594x over previous
//
#include <hip/hip_runtime.h>
#include <stdint.h>

#define N_NODES 50000
#define N_EDGES 200000
#define H 32
#define T_STEPS 8
#define NGROUPS (N_EDGES / 64)   // 3125, exact: no tail handling anywhere
#define SCAN_B 196               // 196*256 = 50176 >= N_NODES

typedef __attribute__((ext_vector_type(4))) float v4f;
typedef __attribute__((ext_vector_type(8))) _Float16 h8;

#define LO_SCALE 4096.0f
#define LO_DESCALE 2.44140625e-4f  // 1/4096

__device__ __forceinline__ uint32_t packh2(_Float16 a, _Float16 b) {
  return (uint32_t)__builtin_bit_cast(unsigned short, a) |
         ((uint32_t)__builtin_bit_cast(unsigned short, b) << 16);
}

// hid[e][d] = relu(edge_data[e].W1[d] + b1[d]), fp16 hi + scaled-lo. (proven)
__global__ void hidb_kernel(const float* __restrict__ ed, const float* __restrict__ W1,
                            const float* __restrict__ b1,
                            uint32_t* __restrict__ hidh, uint32_t* __restrict__ hidl) {
  int idx = blockIdx.x * blockDim.x + threadIdx.x;   // E*32 threads
  int e = idx >> 5, d2 = idx & 31;
  int d0 = d2 * 2;
  const float4* er = (const float4*)(ed + (size_t)e * 16);
  const float4* w0 = (const float4*)(W1 + (size_t)d0 * 16);
  const float4* w1 = (const float4*)(W1 + (size_t)(d0 + 1) * 16);
  float a0 = b1[d0], a1 = b1[d0 + 1];
#pragma unroll
  for (int k = 0; k < 4; k++) {
    float4 h = er[k], u = w0[k], v = w1[k];
    a0 += h.x * u.x + h.y * u.y + h.z * u.z + h.w * u.w;
    a1 += h.x * v.x + h.y * v.y + h.z * v.z + h.w * v.w;
  }
  a0 = fmaxf(a0, 0.f);
  a1 = fmaxf(a1, 0.f);
  _Float16 h0 = (_Float16)a0, h1 = (_Float16)a1;
  _Float16 l0 = (_Float16)((a0 - (float)h0) * LO_SCALE);
  _Float16 l1 = (_Float16)((a1 - (float)h1) * LO_SCALE);
  hidh[idx] = packh2(h0, h1);
  hidl[idx] = packh2(l0, l1);
}

// Pack W2 into MFMA A-fragment-linear fp16 hi / scaled-lo. (proven)
__global__ void w2pack_kernel(const float* __restrict__ W2,
                              uint32_t* __restrict__ W2Fh, uint32_t* __restrict__ W2Fl) {
  int o = blockIdx.x * blockDim.x + threadIdx.x;   // 32768 threads
  int c = o >> 8, u = o & 255;
  int lane = u >> 2, pr = u & 3;
  int mtg = c >> 1, kh = c & 1;
  int row = mtg * 16 + (lane & 15);
  int k = kh * 32 + (lane >> 4) * 8 + pr * 2;
  float v0 = W2[(size_t)row * 64 + k];
  float v1 = W2[(size_t)row * 64 + k + 1];
  _Float16 h0 = (_Float16)v0, h1 = (_Float16)v1;
  _Float16 l0 = (_Float16)((v0 - (float)h0) * LO_SCALE);
  _Float16 l1 = (_Float16)((v1 - (float)h1) * LO_SCALE);
  W2Fh[o] = packh2(h0, h1);
  W2Fl[o] = packh2(l0, l1);
}

// ---------- CSR incidence build; R6: hierarchical 3-phase scan ----------
// R5 post-mortem: single-block scan_kernel = 127us, the largest dispatch in
// the pipeline (1 CU, serial 49-elem loops). Split into 196-block sums ->
// 1-block scan of 196 -> 196-block local scan + base. ~15us total.
__global__ void zero_cur_kernel(int* __restrict__ cur) {
  int i = blockIdx.x * blockDim.x + threadIdx.x;
  if (i < N_NODES) cur[i] = 0;
}
__global__ void count_kernel(const int* __restrict__ edges, int* __restrict__ cur) {
  int e = blockIdx.x * blockDim.x + threadIdx.x;
  if (e < N_EDGES) {
    int s = edges[2 * e], d = edges[2 * e + 1];
    atomicAdd(&cur[s], 1);
    if (d != s) atomicAdd(&cur[d], 1);
  }
}
__global__ __launch_bounds__(256) void bsum_kernel(const int* __restrict__ cur,
                                                   int* __restrict__ bsum) {
  __shared__ int s[256];
  int b = blockIdx.x, t = threadIdx.x;
  int idx = b * 256 + t;
  s[t] = (idx < N_NODES) ? cur[idx] : 0;
  __syncthreads();
  for (int d = 128; d > 0; d >>= 1) {
    if (t < d) s[t] += s[t + d];
    __syncthreads();
  }
  if (t == 0) bsum[b] = s[0];
}
__global__ __launch_bounds__(256) void bscan_kernel(const int* __restrict__ bsum,
                                                    int* __restrict__ bbase,
                                                    int* __restrict__ off) {
  __shared__ int s[256];
  int t = threadIdx.x;
  int v = (t < SCAN_B) ? bsum[t] : 0;
  s[t] = v;
  __syncthreads();
  for (int d = 1; d < 256; d <<= 1) {
    int u = (t >= d) ? s[t - d] : 0;
    __syncthreads();
    s[t] += u;
    __syncthreads();
  }
  if (t < SCAN_B) bbase[t] = s[t] - v;        // exclusive block base
  if (t == SCAN_B - 1) off[N_NODES] = s[t];   // grand total
}
__global__ __launch_bounds__(256) void boff_kernel(const int* __restrict__ bbase,
                                                   int* __restrict__ cur,
                                                   int* __restrict__ off) {
  __shared__ int s[256];
  int b = blockIdx.x, t = threadIdx.x;
  int idx = b * 256 + t;
  int v = (idx < N_NODES) ? cur[idx] : 0;
  s[t] = v;
  __syncthreads();
  for (int d = 1; d < 256; d <<= 1) {
    int u = (t >= d) ? s[t - d] : 0;
    __syncthreads();
    s[t] += u;
    __syncthreads();
  }
  if (idx < N_NODES) {
    int ex = bbase[b] + s[t] - v;   // exclusive prefix
    off[idx] = ex;
    cur[idx] = ex;
  }
}
__global__ void scatter_kernel(const int* __restrict__ edges, int* __restrict__ cur,
                               int* __restrict__ inc) {
  int e = blockIdx.x * blockDim.x + threadIdx.x;
  if (e < N_EDGES) {
    int s = edges[2 * e], d = edges[2 * e + 1];
    int p = atomicAdd(&cur[s], 1);
    inc[p] = e;
    if (d != s) {
      p = atomicAdd(&cur[d], 1);
      inc[p] = e;
    }
  }
}

// ---------- async global->LDS helper (zero VGPR staging) ----------
typedef __attribute__((address_space(1))) const uint32_t gq_u32;
typedef __attribute__((address_space(3))) uint32_t lds_q_u32;
__device__ __forceinline__ void gload_lds16(const uint32_t* g, uint32_t* l) {
  // lds dst: wave-uniform base + lane*16B (hardware); global src per-lane.
  __builtin_amdgcn_global_load_lds((gq_u32*)g, (lds_q_u32*)l, 16, 0, 0);
}

// Stage one W2F eighth (16KB hi + 16KB lo) into LDS buffers bh/bl.
// 4 waves x 4 calls x (64 lanes x 16B) = 16KB per array.
__device__ __forceinline__ void stage_eighth(const uint32_t* __restrict__ W2Fh,
                                             const uint32_t* __restrict__ W2Fl,
                                             uint32_t* bh, uint32_t* bl,
                                             int eighth, int wv, int lane) {
#pragma unroll
  for (int k = 0; k < 4; k++) {
    int ub = (wv * 4 + k) * 256;          // wave-uniform lds base (uint32 units)
    int u  = ub + lane * 4;               // per-lane global index (16B per lane)
    gload_lds16(W2Fh + eighth * 4096 + u, bh + ub);
    gload_lds16(W2Fl + eighth * 4096 + u, bl + ub);
  }
}

// ---------- message build R6: R5 structure, 4 edge-groups per W2 pass ----
// R5 confirmed LDS-read amortization (2-group: 1803->1688). Extend to 4
// groups (256 edges/pass): each ds_read_b128 fragment feeds 24 MFMAs,
// passes per block drop 3.05 -> 2, per-edge LDS cycles halve again.
// All set-indexed arrays are accessed only under full #pragma unroll with
// loop-constant indices (rule: runtime-indexed ext_vector arrays -> scratch).
// Tail: sets clamp to last group (duplicate compute), stores gated.
// VGPR ~190 under the 256 budget at 2 waves/SIMD (launch_bounds(256,2)).
__global__ __launch_bounds__(256, 2) void msg_kernel(
    const uint32_t* __restrict__ W2Fh, const uint32_t* __restrict__ W2Fl,
    const uint32_t* __restrict__ hidh, const uint32_t* __restrict__ hidl,
    const float* __restrict__ b2, const float* __restrict__ x,
    const int* __restrict__ edges, float* __restrict__ msg) {
  __shared__ uint32_t w2h[2][4096];   // 2 x 16KB: eighth double-buffer, hi
  __shared__ uint32_t w2l[2][4096];   // 2 x 16KB: scaled lo
  __shared__ float b2s[1024];
  int t = threadIdx.x;
  int bid = blockIdx.x;
  // contiguous group range per block: grid 512 (exactly resident at 2/CU)
  int gs = (int)(((long)bid * NGROUPS) >> 9);
  int ge = (int)(((long)(bid + 1) * NGROUPS) >> 9);
  int wv = t >> 6, lane = t & 63;
  int el = lane & 15, kg = lane >> 4;

  for (int i = t; i < 1024; i += 256) b2s[i] = b2[i];
  // prologue: stage eighth 0 into buffer 0
  stage_eighth(W2Fh, W2Fl, w2h[0], w2l[0], 0, wv, lane);
  __syncthreads();

  const h8* hbh = (const h8*)hidh;
  const h8* hbl = (const h8*)hidl;
  int cb = 0;

  for (int g = gs; g < ge; g += 4) {
    int ee[4];
    h8 bh0[4], bh1[4], bl0[4], bl1[4];
    v4f xv0[4], xv1[4];
#pragma unroll
    for (int u = 0; u < 4; u++) {
      int gu = g + u < ge ? g + u : ge - 1;   // clamp tail to last real group
      int e = gu * 64 + wv * 16 + el;         // < 200000 always
      ee[u] = e;
      int src = edges[2 * e];
      bh0[u] = hbh[(size_t)e * 8 + kg];
      bh1[u] = hbh[(size_t)e * 8 + 4 + kg];
      bl0[u] = hbl[(size_t)e * 8 + kg];
      bl1[u] = hbl[(size_t)e * 8 + 4 + kg];
      xv0[u] = *(const v4f*)(x + (size_t)src * 32 + kg * 4);
      xv1[u] = *(const v4f*)(x + (size_t)src * 32 + 16 + kg * 4);
    }

    for (int s = 0; s < 8; ++s) {
      // issue next eighth's async staging into the other buffer
      if (!(s == 7 && g + 4 >= ge)) {
        stage_eighth(W2Fh, W2Fl, w2h[cb ^ 1], w2l[cb ^ 1], (s + 1) & 7, wv, lane);
      }
      int q = s >> 1, h = s & 1;
      const h8* sh = (const h8*)w2h[cb];
      const h8* sl = (const h8*)w2l[cb];
      const float* b2p = b2s + q * 256 + h * 128 + kg * 4;

      float sacc[4][4];   // [set][mp2]
#pragma unroll
      for (int mp2 = 0; mp2 < 4; mp2++) {
        float tacc[4] = {0.f, 0.f, 0.f, 0.f};
#pragma unroll
        for (int tp = 0; tp < 2; tp++) {
          int lm = 2 * mp2 + tp;   // within-eighth M-tile, 0..7
          h8 ah0 = sh[(size_t)(lm * 2 + 0) * 64 + lane];
          h8 ah1 = sh[(size_t)(lm * 2 + 1) * 64 + lane];
          h8 al0 = sl[(size_t)(lm * 2 + 0) * 64 + lane];
          h8 al1 = sl[(size_t)(lm * 2 + 1) * 64 + lane];
          v4f bias = *(const v4f*)(b2p + lm * 16);
#pragma unroll
          for (int u = 0; u < 4; u++) {
            v4f chi = bias;
            chi = __builtin_amdgcn_mfma_f32_16x16x32_f16(ah0, bh0[u], chi, 0, 0, 0);
            chi = __builtin_amdgcn_mfma_f32_16x16x32_f16(ah1, bh1[u], chi, 0, 0, 0);
            v4f clo = {0.f, 0.f, 0.f, 0.f};
            clo = __builtin_amdgcn_mfma_f32_16x16x32_f16(ah0, bl0[u], clo, 0, 0, 0);
            clo = __builtin_amdgcn_mfma_f32_16x16x32_f16(ah1, bl1[u], clo, 0, 0, 0);
            clo = __builtin_amdgcn_mfma_f32_16x16x32_f16(al0, bh0[u], clo, 0, 0, 0);
            clo = __builtin_amdgcn_mfma_f32_16x16x32_f16(al1, bh1[u], clo, 0, 0, 0);
            v4f xr = tp ? xv1[u] : xv0[u];
#pragma unroll
            for (int r = 0; r < 4; r++) {
              float av = fmaxf(fmaf(clo[r], LO_DESCALE, chi[r]), 0.f);
              tacc[u] = fmaf(av, xr[r], tacc[u]);
            }
          }
        }
#pragma unroll
        for (int u = 0; u < 4; u++) {
          float sv = tacc[u];
          sv += __shfl_xor(sv, 16, 64);
          sv += __shfl_xor(sv, 32, 64);
          sacc[u][mp2] = sv;   // msg value for (ee[u], i = q*8 + h*4 + mp2)
        }
      }
      if (lane < 16) {
#pragma unroll
        for (int u = 0; u < 4; u++) {
          if (g + u < ge) {   // suppress duplicated-tail stores
            v4f sv4 = {sacc[u][0], sacc[u][1], sacc[u][2], sacc[u][3]};
            *(v4f*)(msg + (size_t)ee[u] * 32 + q * 8 + h * 4) = sv4;
          }
        }
      }
      __syncthreads();   // drains global_load_lds (vmcnt) + LDS ops
      cb ^= 1;
    }
  }
}

// ---------- per-iteration: CSR gather + GRU, fused (proven R11; gather
// adapted to edge-major msg: one 128B line per incident edge) ----------
__global__ __launch_bounds__(512) void node_kernel(
    float* __restrict__ x, const float* __restrict__ msg,
    const int* __restrict__ off, const int* __restrict__ inc,
    const float* __restrict__ W_ih, const float* __restrict__ W_hh,
    const float* __restrict__ b_ih, const float* __restrict__ b_hh) {
  __shared__ float wih[64 * 97];   // wih[k*97+q] = W_ih[q][k]
  __shared__ float whh[32 * 97];
  __shared__ float xs[16][32], ms[16][32];
  int t = threadIdx.x;
  for (int p = t; p < 6144; p += 512) {
    int q = p >> 6, k = p & 63;
    wih[k * 97 + q] = W_ih[p];
  }
  for (int p = t; p < 3072; p += 512) {
    int q = p >> 5, k = p & 31;
    whh[k * 97 + q] = W_hh[p];
  }
  int slot = t >> 5, i = t & 31;
  int n = blockIdx.x * 16 + slot;   // 3125*16 = 50000 exact
  float xv = x[(size_t)n * 32 + i];
  xs[slot][i] = xv;
  float acc = 0.f;
  int s0 = off[n], s1 = off[n + 1];
  for (int k = s0; k < s1; k++) {
    int e = inc[k];
    acc += msg[(size_t)e * 32 + i];   // edge-major: lanes 0..31 = one 128B line
  }
  ms[slot][i] = acc;
  __syncthreads();

  float gir = b_ih[i], giz = b_ih[32 + i], gin = b_ih[64 + i];
  float ghr = b_hh[i], ghz = b_hh[32 + i], ghn = b_hh[64 + i];
#pragma unroll 4
  for (int k = 0; k < 32; k++) {
    float xk = xs[slot][k];
    float mk = ms[slot][k];
    const float* wa = &wih[k * 97];          // W_ih[.][k]     (x part)
    const float* wb = &wih[(32 + k) * 97];   // W_ih[.][32+k]  (m part)
    gir += xk * wa[i] + mk * wb[i];
    giz += xk * wa[32 + i] + mk * wb[32 + i];
    gin += xk * wa[64 + i] + mk * wb[64 + i];
    const float* hc = &whh[k * 97];
    ghr += xk * hc[i];
    ghz += xk * hc[32 + i];
    ghn += xk * hc[64 + i];
  }
  float r = 1.f / (1.f + __expf(-(gir + ghr)));
  float z = 1.f / (1.f + __expf(-(giz + ghz)));
  float nn = tanhf(gin + r * ghn);
  x[(size_t)n * 32 + i] = (1.f - z) * nn + z * xv;
}

__global__ void copy4_kernel(float4* __restrict__ dst, const float4* __restrict__ src, int n4) {
  int i = blockIdx.x * blockDim.x + threadIdx.x;
  if (i < n4) dst[i] = src[i];
}

extern "C" void kernel_launch(void* const* d_in, const int* in_sizes, int n_in,
                              void* d_out, int out_size, void* d_ws, size_t ws_size,
                              hipStream_t stream) {
  const float* x_in      = (const float*)d_in[0];
  const float* edge_data = (const float*)d_in[1];
  const int*   edges     = (const int*)d_in[2];
  // d_in[3] = T (always 8; hard-coded)
  const float* W1   = (const float*)d_in[4];
  const float* b1   = (const float*)d_in[5];
  const float* W2   = (const float*)d_in[6];
  const float* b2   = (const float*)d_in[7];
  const float* W_ih = (const float*)d_in[8];
  const float* W_hh = (const float*)d_in[9];
  const float* b_ih = (const float*)d_in[10];
  const float* b_hh = (const float*)d_in[11];

  // Workspace ~79.07 MB (< 83.59 MB proven bound):
  // hidh 25.6M | hidl 25.6M | W2F 256K | inc 1.6M | off | cur | bsum/bbase | msg 25.6M
  char* ws = (char*)d_ws;
  size_t o = 0;
  uint32_t* hidh = (uint32_t*)(ws + o); o += (size_t)N_EDGES * 64 * 2;
  uint32_t* hidl = (uint32_t*)(ws + o); o += (size_t)N_EDGES * 64 * 2;
  uint32_t* W2Fh = (uint32_t*)(ws + o); o += 32768u * 4;
  uint32_t* W2Fl = (uint32_t*)(ws + o); o += 32768u * 4;
  int*      inc  = (int*)(ws + o);      o += (size_t)2 * N_EDGES * 4;
  int*      off  = (int*)(ws + o);      o += (size_t)(N_NODES + 4) * 4;
  int*      cur  = (int*)(ws + o);      o += (size_t)N_NODES * 4;
  int*      bsum = (int*)(ws + o);      o += (size_t)256 * 4;
  int*      bbase= (int*)(ws + o);      o += (size_t)256 * 4;
  float*    msg  = (float*)(ws + o);    o += (size_t)N_EDGES * 32 * 4;
  float*    x    = (float*)d_out;   // iterate x in-place in d_out

  const int n4x = N_NODES * H / 4;  // 400000
  copy4_kernel<<<(n4x + 255) / 256, 256, 0, stream>>>((float4*)x, (const float4*)x_in, n4x);
  hidb_kernel<<<N_EDGES * 32 / 256, 256, 0, stream>>>(edge_data, W1, b1, hidh, hidl);
  w2pack_kernel<<<32768 / 256, 256, 0, stream>>>(W2, W2Fh, W2Fl);

  zero_cur_kernel<<<(N_NODES + 255) / 256, 256, 0, stream>>>(cur);
  count_kernel<<<(N_EDGES + 255) / 256, 256, 0, stream>>>(edges, cur);
  bsum_kernel<<<SCAN_B, 256, 0, stream>>>(cur, bsum);
  bscan_kernel<<<1, 256, 0, stream>>>(bsum, bbase, off);
  boff_kernel<<<SCAN_B, 256, 0, stream>>>(bbase, cur, off);
  scatter_kernel<<<(N_EDGES + 255) / 256, 256, 0, stream>>>(edges, cur, inc);

  for (int it = 0; it < T_STEPS; it++) {
    msg_kernel<<<512, 256, 0, stream>>>(W2Fh, W2Fl, hidh, hidl, b2, x, edges, msg);
    node_kernel<<<N_NODES / 16, 512, 0, stream>>>(x, msg, off, inc,
                                                  W_ih, W_hh, b_ih, b_hh);
  }
}